// Round 4
// baseline (177.016 us; speedup 1.0000x reference)
//
#include <hip/hip_runtime.h>
#include <hip/hip_bf16.h>
#include <cstdint>
#include <cstddef>

#define INDIM  256
#define HD     192   // H*D
#define NHEADS 3
#define NEG_SLOPE 0.2f
#define ELLPAD 96    // max per-node degree bound (Poisson(32): P >= 96 ~ 1e-20)
#define LPAD   97    // LDS ELL row stride (pad to break bank aliasing)
#define BSHIFT 4     // 16 nodes per bucket
#define BNODES 16
#define NBUCKP 1280  // padded bucket count (20000/16 = 1250)
#define BCAP   704   // bucket capacity: mean 512, +8.5 sigma
#define P1CHUNK 8192 // edges per phase-1 block (keeps per-bucket runs >= ~6 edges)

typedef __attribute__((ext_vector_type(8))) short short8;
typedef __attribute__((ext_vector_type(4))) float f32x4;

__device__ __forceinline__ float wave_sum(float v) {
#pragma unroll
    for (int o = 32; o; o >>= 1) v += __shfl_xor(v, o, 64);
    return v;
}

// ---------------------------------------------------------------------------
// K0: prep — block 0 zeros bucket cursors; blocks 1..192 build Wt (bf16, T).
// ---------------------------------------------------------------------------
__global__ __launch_bounds__(256) void prep_kernel(
    const float* __restrict__ W, __hip_bfloat16* __restrict__ Wt,
    int* __restrict__ gCur)
{
    const int b = blockIdx.x, tid = threadIdx.x;
    if (b == 0) {
        for (int i = tid; i < NBUCKP; i += 256) gCur[i] = 0;
        return;
    }
    int n = b - 1;   // 0..191
    Wt[n * 256 + tid] = __float2bfloat16(W[tid * HD + n]);
}

// ---------------------------------------------------------------------------
// K1: fused MFMA GEMM (+el/er epilogue) and phase-1 edge bucketing.
// GEMM: one block = 64 rows x all 192 cols; feat+Wt staged with one-K-step
// software prefetch (loads issued between LDS stores and the compute barrier
// so HBM latency hides under the MFMA phase — round-1 counters showed the
// K-loop serialized on the cold feat load: VALUBusy 3%, MfmaUtil 1.4%).
// Bucketing: 8192 edges/block, two-pass (histogram -> base -> scatter) so
// pair writes land in ~6-edge dense runs per bucket (no 4B random scatter).
// ---------------------------------------------------------------------------
__global__ __launch_bounds__(256) void gemm_bucket_kernel(
    const float* __restrict__ feat,         // [M,256] fp32
    const __hip_bfloat16* __restrict__ Wt,  // [192,256] bf16 (n-major)
    const float* __restrict__ attn_l, const float* __restrict__ attn_r,
    __hip_bfloat16* __restrict__ hb, float* __restrict__ el,
    float* __restrict__ er, int M,
    const int* __restrict__ src, const int* __restrict__ dst,
    int* __restrict__ gCur, int2* __restrict__ pairs,
    int E, int gemmBlocks)
{
    const int tid = threadIdx.x;
    if (blockIdx.x >= gemmBlocks) {
        // ---------------- phase-1 bucketing (two-pass) ----------------
        __shared__ int cnt[NBUCKP];
        __shared__ int cnt2[NBUCKP];
        __shared__ int base[NBUCKP];
        const int e0 = (blockIdx.x - gemmBlocks) * P1CHUNK;
        for (int i = tid; i < NBUCKP; i += 256) { cnt[i] = 0; cnt2[i] = 0; }
        __syncthreads();
        for (int u = 0; u < P1CHUNK / 256; u++) {
            int e = e0 + u * 256 + tid;
            if (e < E) atomicAdd(&cnt[dst[e] >> BSHIFT], 1);
        }
        __syncthreads();
        for (int i = tid; i < NBUCKP; i += 256)
            if (cnt[i] > 0) base[i] = atomicAdd(&gCur[i], cnt[i]);
        __syncthreads();
        for (int u = 0; u < P1CHUNK / 256; u++) {
            int e = e0 + u * 256 + tid;
            if (e < E) {
                int d = dst[e];
                int b = d >> BSHIFT;
                int l = atomicAdd(&cnt2[b], 1);
                int idx = base[b] + l;
                if (idx < BCAP)
                    pairs[(size_t)b * BCAP + idx] = make_int2(d, src[e]);
            }
        }
        return;
    }
    // ---------------- GEMM part ----------------
    __shared__ __hip_bfloat16 As[64][40];
    __shared__ __hip_bfloat16 Bs[192][40];
    const int lane = tid & 63, w = tid >> 6;
    const int q = lane >> 4, ll = lane & 15;
    const int row0 = blockIdx.x * 64;

    f32x4 acc[12];   // acc[head*4+f] -> cols (head*4+f)*16+ll
#pragma unroll
    for (int c = 0; c < 12; c++) acc[c] = (f32x4){0.f, 0.f, 0.f, 0.f};

    const int sr = tid >> 2, sk = (tid & 3) * 8;  // A staging: 64 rows x 32 k
    const int grow = row0 + sr;
    const bool arow = grow < M;
    const float* ap = feat + (size_t)grow * INDIM + sk;
    const __hip_bfloat16* bp = Wt + (size_t)tid * INDIM;

    // prefetch K-step 0
    float4 a0 = make_float4(0.f, 0.f, 0.f, 0.f), a1 = a0;
    if (arow) { a0 = *(const float4*)ap; a1 = *(const float4*)(ap + 4); }
    uint4 b0, b1, b2, b3;
    if (tid < HD) {
        b0 = *(const uint4*)(bp);      b1 = *(const uint4*)(bp + 8);
        b2 = *(const uint4*)(bp + 16); b3 = *(const uint4*)(bp + 24);
    }

    for (int k0 = 0; k0 < INDIM; k0 += 32) {
        __hip_bfloat16 ab[8] = {__float2bfloat16(a0.x), __float2bfloat16(a0.y),
                                __float2bfloat16(a0.z), __float2bfloat16(a0.w),
                                __float2bfloat16(a1.x), __float2bfloat16(a1.y),
                                __float2bfloat16(a1.z), __float2bfloat16(a1.w)};
        __syncthreads();   // previous iteration's LDS reads done
        *(uint4*)&As[sr][sk] = *(const uint4*)ab;
        if (tid < HD) {
            *(uint4*)&Bs[tid][0]  = b0;
            *(uint4*)&Bs[tid][8]  = b1;
            *(uint4*)&Bs[tid][16] = b2;
            *(uint4*)&Bs[tid][24] = b3;
        }
        // issue next K-step's loads now; latency hides under barrier + MFMA
        if (k0 + 32 < INDIM) {
            if (arow) {
                a0 = *(const float4*)(ap + k0 + 32);
                a1 = *(const float4*)(ap + k0 + 36);
            }
            if (tid < HD) {
                const __hip_bfloat16* bq = bp + k0 + 32;
                b0 = *(const uint4*)(bq);      b1 = *(const uint4*)(bq + 8);
                b2 = *(const uint4*)(bq + 16); b3 = *(const uint4*)(bq + 24);
            }
        }
        __syncthreads();

        short8 af = *(const short8*)&As[w * 16 + ll][q * 8];
#pragma unroll
        for (int c = 0; c < 12; c++) {
            short8 bf = *(const short8*)&Bs[c * 16 + ll][q * 8];
            acc[c] = __builtin_amdgcn_mfma_f32_16x16x32_bf16(af, bf, acc[c], 0, 0, 0);
        }
    }

    // ---- epilogue: el/er (full head dots) + hb store ----
    float al[12], ar[12];
#pragma unroll
    for (int c = 0; c < 12; c++) {
        al[c] = attn_l[c * 16 + ll];
        ar[c] = attn_r[c * 16 + ll];
    }
    float sl[3][4], sr_[3][4];
#pragma unroll
    for (int hd = 0; hd < 3; hd++)
#pragma unroll
        for (int i = 0; i < 4; i++) {
            float a = 0.f, b = 0.f;
#pragma unroll
            for (int f = 0; f < 4; f++) {
                a = fmaf(acc[hd * 4 + f][i], al[hd * 4 + f], a);
                b = fmaf(acc[hd * 4 + f][i], ar[hd * 4 + f], b);
            }
            sl[hd][i] = a; sr_[hd][i] = b;
        }
#pragma unroll
    for (int hd = 0; hd < 3; hd++)
#pragma unroll
        for (int i = 0; i < 4; i++)
#pragma unroll
            for (int off = 1; off < 16; off <<= 1) {
                sl[hd][i]  += __shfl_xor(sl[hd][i],  off, 64);
                sr_[hd][i] += __shfl_xor(sr_[hd][i], off, 64);
            }
#pragma unroll
    for (int c = 0; c < 12; c++)
#pragma unroll
        for (int i = 0; i < 4; i++) {
            int row = row0 + w * 16 + q * 4 + i;
            if (row < M)
                hb[(size_t)row * HD + c * 16 + ll] = __float2bfloat16(acc[c][i]);
        }
    if (ll == 0) {
#pragma unroll
        for (int i = 0; i < 4; i++) {
            int row = row0 + w * 16 + q * 4 + i;
            if (row < M) {
#pragma unroll
                for (int hd = 0; hd < 3; hd++) {
                    el[row * 4 + hd] = sl[hd][i];    // padded float4 stride
                    er[row * 4 + hd] = sr_[hd][i];
                }
            }
        }
    }
}

// ---------------------------------------------------------------------------
// K2: fused bucket kernel — per 16-node bucket: read the bucket's dense
// (dst,src) run, rank via LDS cursors into a 6KB LDS ELL, then 4 waves x
// 4 nodes each run softmax + aggregation + bias/relu + fc dot.
// 1250 blocks x 256 threads: ~4.9 blocks/CU, so no 2x makespan tail
// (round-3's 313x1024 grid left most CUs idle half the kernel).
// ---------------------------------------------------------------------------
__global__ __launch_bounds__(256) void gat_bucket_kernel(
    const __hip_bfloat16* __restrict__ h, const float* __restrict__ el,
    const float* __restrict__ er, const int2* __restrict__ pairs,
    const int* __restrict__ gCur, const float* __restrict__ gbias,
    const float* __restrict__ fc_w, float* __restrict__ pA,
    float* __restrict__ pB, int N)
{
    __shared__ int cur[BNODES];
    __shared__ int lell[BNODES][LPAD];
    __shared__ float4 sE[4][64];   // per-wave edge slots: (s_bits, w0, w1, w2)

    const int b = blockIdx.x;
    const int tid = threadIdx.x;
    const int lane = tid & 63, wslot = tid >> 6;

    if (tid < BNODES) cur[tid] = 0;
    __syncthreads();
    const int pcnt = min(gCur[b], BCAP);
    const int2* pp = pairs + (size_t)b * BCAP;
    for (int i = tid; i < pcnt; i += 256) {
        int2 p = pp[i];
        int nl = p.x & (BNODES - 1);
        int r = atomicAdd(&cur[nl], 1);
        if (r < ELLPAD) lell[nl][r] = p.y;
    }
    __syncthreads();

    const __hip_bfloat16* hl = h + lane;

#pragma unroll 1
    for (int k = 0; k < 4; k++) {
        const int nl = (wslot << 2) + k;
        const int v = (b << BSHIFT) + nl;
        if (v >= N) continue;

        const int cnt = min(cur[nl], ELLPAD);
        const int* rowp = &lell[nl][0];
        const float4 erv = ((const float4*)er)[v];
        const float er0 = erv.x, er1 = erv.y, er2 = erv.z;

        float acc0 = 0.f, acc1 = 0.f, acc2 = 0.f;
        float d0 = 0.f, d1 = 0.f, d2 = 0.f;

        for (int chunk = 0; chunk < cnt; chunk += 64) {
            const int i = chunk + lane;
            float w0 = 0.f, w1 = 0.f, w2 = 0.f;
            int s = 0;
            if (i < cnt) {
                s = rowp[i];                         // LDS read
                const float4 le = ((const float4*)el)[s];
                float l0 = le.x + er0;
                float l1 = le.y + er1;
                float l2 = le.z + er2;
                l0 = l0 > 0.f ? l0 : NEG_SLOPE * l0;
                l1 = l1 > 0.f ? l1 : NEG_SLOPE * l1;
                l2 = l2 > 0.f ? l2 : NEG_SLOPE * l2;
                w0 = __expf(l0); w1 = __expf(l1); w2 = __expf(l2);
            }
            d0 += w0; d1 += w1; d2 += w2;
            sE[wslot][lane] = make_float4(__int_as_float(s), w0, w1, w2);
            // same-wave LDS write->read; drain DS queue before readback:
            __asm__ volatile("s_waitcnt lgkmcnt(0)" ::: "memory");

            const int rem = min(cnt - chunk, 64);
            const int nR = (rem + 7) & ~7;   // pad entries have w=0, s=0
            for (int j = 0; j < nR; j += 8) {
                float4 e[8];
#pragma unroll
                for (int u = 0; u < 8; u++) e[u] = sE[wslot][j + u];
                float x0[8], x1[8], x2[8];
#pragma unroll
                for (int u = 0; u < 8; u++) {
                    const __hip_bfloat16* p = hl + (size_t)__float_as_int(e[u].x) * HD;
                    x0[u] = __bfloat162float(p[0]);
                    x1[u] = __bfloat162float(p[64]);
                    x2[u] = __bfloat162float(p[128]);
                }
#pragma unroll
                for (int u = 0; u < 8; u++) {
                    acc0 = fmaf(e[u].y, x0[u], acc0);
                    acc1 = fmaf(e[u].z, x1[u], acc1);
                    acc2 = fmaf(e[u].w, x2[u], acc2);
                }
            }
        }

        d0 = wave_sum(d0); d1 = wave_sum(d1); d2 = wave_sum(d2);

        float o0 = (d0 > 0.f) ? acc0 / d0 : 0.f;
        float o1 = (d1 > 0.f) ? acc1 / d1 : 0.f;
        float o2 = (d2 > 0.f) ? acc2 / d2 : 0.f;
        o0 = fmaxf(o0 + gbias[lane], 0.f);
        o1 = fmaxf(o1 + gbias[64 + lane], 0.f);
        o2 = fmaxf(o2 + gbias[128 + lane], 0.f);

        const size_t bidx = (size_t)v * HD;
        float2 w0v = ((const float2*)fc_w)[bidx + lane];
        float2 w1v = ((const float2*)fc_w)[bidx + 64 + lane];
        float2 w2v = ((const float2*)fc_w)[bidx + 128 + lane];
        float f0 = fmaf(o0, w0v.x, fmaf(o1, w1v.x, o2 * w2v.x));
        float f1 = fmaf(o0, w0v.y, fmaf(o1, w1v.y, o2 * w2v.y));

        f0 = wave_sum(f0); f1 = wave_sum(f1);
        if (lane == 0) { pA[v] = f0; pB[v] = f1; }
    }
}

// ---------------------------------------------------------------------------
// K4: final reduction of per-node partials -> out (adds fc bias; no atomics)
// ---------------------------------------------------------------------------
__global__ __launch_bounds__(1024) void final_reduce(const float* __restrict__ pA,
                                                     const float* __restrict__ pB,
                                                     const float* __restrict__ fc_b,
                                                     float* __restrict__ out, int nb)
{
    int tid = threadIdx.x;
    float s0 = 0.f, s1 = 0.f;
    for (int i = tid; i < nb; i += 1024) { s0 += pA[i]; s1 += pB[i]; }
    s0 = wave_sum(s0); s1 = wave_sum(s1);
    __shared__ float sh[32];
    int lane = tid & 63, w = tid >> 6;
    if (lane == 0) { sh[w * 2] = s0; sh[w * 2 + 1] = s1; }
    __syncthreads();
    if (tid == 0) {
        float t0 = 0.f, t1 = 0.f;
#pragma unroll
        for (int i = 0; i < 16; i++) { t0 += sh[i * 2]; t1 += sh[i * 2 + 1]; }
        out[0] = t0 + fc_b[0];
        out[1] = t1 + fc_b[1];
    }
}

// ---------------------------------------------------------------------------
extern "C" void kernel_launch(void* const* d_in, const int* in_sizes, int n_in,
                              void* d_out, int out_size, void* d_ws, size_t ws_size,
                              hipStream_t stream)
{
    const float* feat   = (const float*)d_in[0];
    const float* W      = (const float*)d_in[1];
    const float* attn_l = (const float*)d_in[2];
    const float* attn_r = (const float*)d_in[3];
    const float* gbias  = (const float*)d_in[4];
    const float* fc_w   = (const float*)d_in[5];
    const float* fc_b   = (const float*)d_in[6];
    const int*   src    = (const int*)d_in[7];
    const int*   dst    = (const int*)d_in[8];

    const int N = in_sizes[0] / INDIM;   // 20000
    const int E = in_sizes[7];           // 640000
    const int nBuck = (N + BNODES - 1) >> BSHIFT;   // 1250

    // workspace layout (~16 MB, all sub-arrays 16B-aligned)
    __hip_bfloat16* Wt = (__hip_bfloat16*)d_ws;             // 192*256       (96 KB)
    __hip_bfloat16* hb = Wt + HD * INDIM;                   // N*192         (7.68 MB)
    float* el = (float*)(hb + (size_t)N * HD);              // N*4 (padded)
    float* er = el + (size_t)N * 4;                         // N*4 (padded)
    int* gCur = (int*)(er + (size_t)N * 4);                 // NBUCKP (1280)
    int2* pairs = (int2*)(gCur + NBUCKP);                   // NBUCKP*BCAP   (7.2 MB)
    float* pA = (float*)(pairs + (size_t)NBUCKP * BCAP);    // N
    float* pB = pA + N;                                     // N

    prep_kernel<<<1 + HD, 256, 0, stream>>>(W, Wt, gCur);

    const int gemmBlocks = (N + 63) / 64;
    const int p1Blocks = (E + P1CHUNK - 1) / P1CHUNK;
    gemm_bucket_kernel<<<gemmBlocks + p1Blocks, 256, 0, stream>>>(
        feat, Wt, attn_l, attn_r, hb, el, er, N,
        src, dst, gCur, pairs, E, gemmBlocks);

    gat_bucket_kernel<<<nBuck, 256, 0, stream>>>(hb, el, er, pairs, gCur,
                                                 gbias, fc_w, pA, pB, N);
    final_reduce<<<1, 1024, 0, stream>>>(pA, pB, fc_b, (float*)d_out, N);
}

// Round 5
// 165.459 us; speedup vs baseline: 1.0698x; 1.0698x over previous
//
#include <hip/hip_runtime.h>
#include <hip/hip_bf16.h>
#include <cstdint>
#include <cstddef>

#define INDIM  256
#define HD     192   // H*D
#define NHEADS 3
#define NEG_SLOPE 0.2f
#define ELLPAD 96    // max per-node degree bound (Poisson(32): P >= 96 ~ 1e-20)
#define LPAD   97    // LDS ELL row stride (pad to break bank aliasing)
#define CSHIFT 7     // coarse bucket = 128 nodes (phase-1 granularity)
#define NBUCK  160   // ceil(20000/128)=157, padded
#define BCAP   4608  // coarse bucket capacity: mean 4096, +8 sigma
#define FNODES 16    // fine nodes per K2 block (consume granularity)
#define P1CHUNK 2048 // edges per phase-1 block (313 blocks; short LDS-atomic chains)

typedef __attribute__((ext_vector_type(8))) short short8;
typedef __attribute__((ext_vector_type(4))) float f32x4;

__device__ __forceinline__ float wave_sum(float v) {
#pragma unroll
    for (int o = 32; o; o >>= 1) v += __shfl_xor(v, o, 64);
    return v;
}

// ---------------------------------------------------------------------------
// K0: prep — block 0 zeros bucket cursors; blocks 1..192 build Wt (bf16, T).
// ---------------------------------------------------------------------------
__global__ __launch_bounds__(256) void prep_kernel(
    const float* __restrict__ W, __hip_bfloat16* __restrict__ Wt,
    int* __restrict__ gCur)
{
    const int b = blockIdx.x, tid = threadIdx.x;
    if (b == 0) {
        if (tid < NBUCK) gCur[tid] = 0;
        return;
    }
    int n = b - 1;   // 0..191
    Wt[n * 256 + tid] = __float2bfloat16(W[tid * HD + n]);
}

// ---------------------------------------------------------------------------
// K1: fused MFMA GEMM (+el/er epilogue) and phase-1 edge bucketing.
// GEMM: one block = 64 rows x all 192 cols; one-K-step software prefetch.
// Bucketing (round-0 proven shape, restored): 313 blocks x 2048 edges into
// 160 COARSE buckets (128 nodes) — per-block LDS atomics 2K (not 16K),
// ranks carried in registers, pair runs ~13 edges (no write amplification).
// Every K1 variant with fine-bucket/long-block phase-1 pinned at ~47-50us;
// this isolates whether phase-1 serialization was the wall.
// ---------------------------------------------------------------------------
__global__ __launch_bounds__(256) void gemm_bucket_kernel(
    const float* __restrict__ feat,         // [M,256] fp32
    const __hip_bfloat16* __restrict__ Wt,  // [192,256] bf16 (n-major)
    const float* __restrict__ attn_l, const float* __restrict__ attn_r,
    __hip_bfloat16* __restrict__ hb, float* __restrict__ el,
    float* __restrict__ er, int M,
    const int* __restrict__ src, const int* __restrict__ dst,
    int* __restrict__ gCur, int2* __restrict__ pairs,
    int E, int gemmBlocks)
{
    const int tid = threadIdx.x;
    if (blockIdx.x >= gemmBlocks) {
        // ---------------- phase-1 coarse bucketing ----------------
        __shared__ int cnt[NBUCK];
        __shared__ int base[NBUCK];
        const int e0 = (blockIdx.x - gemmBlocks) * P1CHUNK;
        if (tid < NBUCK) cnt[tid] = 0;
        __syncthreads();
        int d[8], s[8], b[8], l[8];
#pragma unroll
        for (int u = 0; u < 8; u++) {
            int e = e0 + u * 256 + tid;
            if (e < E) {
                d[u] = dst[e]; s[u] = src[e];
                b[u] = d[u] >> CSHIFT;
                l[u] = atomicAdd(&cnt[b[u]], 1);
            } else b[u] = -1;
        }
        __syncthreads();
        if (tid < NBUCK && cnt[tid] > 0) base[tid] = atomicAdd(&gCur[tid], cnt[tid]);
        __syncthreads();
#pragma unroll
        for (int u = 0; u < 8; u++) {
            if (b[u] >= 0) {
                int idx = base[b[u]] + l[u];
                if (idx < BCAP)
                    pairs[(size_t)b[u] * BCAP + idx] = make_int2(d[u], s[u]);
            }
        }
        return;
    }
    // ---------------- GEMM part ----------------
    __shared__ __hip_bfloat16 As[64][40];
    __shared__ __hip_bfloat16 Bs[192][40];
    const int lane = tid & 63, w = tid >> 6;
    const int q = lane >> 4, ll = lane & 15;
    const int row0 = blockIdx.x * 64;

    f32x4 acc[12];   // acc[head*4+f] -> cols (head*4+f)*16+ll
#pragma unroll
    for (int c = 0; c < 12; c++) acc[c] = (f32x4){0.f, 0.f, 0.f, 0.f};

    const int sr = tid >> 2, sk = (tid & 3) * 8;  // A staging: 64 rows x 32 k
    const int grow = row0 + sr;
    const bool arow = grow < M;
    const float* ap = feat + (size_t)grow * INDIM + sk;
    const __hip_bfloat16* bp = Wt + (size_t)tid * INDIM;

    // prefetch K-step 0
    float4 a0 = make_float4(0.f, 0.f, 0.f, 0.f), a1 = a0;
    if (arow) { a0 = *(const float4*)ap; a1 = *(const float4*)(ap + 4); }
    uint4 b0, b1, b2, b3;
    if (tid < HD) {
        b0 = *(const uint4*)(bp);      b1 = *(const uint4*)(bp + 8);
        b2 = *(const uint4*)(bp + 16); b3 = *(const uint4*)(bp + 24);
    }

    for (int k0 = 0; k0 < INDIM; k0 += 32) {
        __hip_bfloat16 ab[8] = {__float2bfloat16(a0.x), __float2bfloat16(a0.y),
                                __float2bfloat16(a0.z), __float2bfloat16(a0.w),
                                __float2bfloat16(a1.x), __float2bfloat16(a1.y),
                                __float2bfloat16(a1.z), __float2bfloat16(a1.w)};
        __syncthreads();   // previous iteration's LDS reads done
        *(uint4*)&As[sr][sk] = *(const uint4*)ab;
        if (tid < HD) {
            *(uint4*)&Bs[tid][0]  = b0;
            *(uint4*)&Bs[tid][8]  = b1;
            *(uint4*)&Bs[tid][16] = b2;
            *(uint4*)&Bs[tid][24] = b3;
        }
        // issue next K-step's loads now; latency hides under barrier + MFMA
        if (k0 + 32 < INDIM) {
            if (arow) {
                a0 = *(const float4*)(ap + k0 + 32);
                a1 = *(const float4*)(ap + k0 + 36);
            }
            if (tid < HD) {
                const __hip_bfloat16* bq = bp + k0 + 32;
                b0 = *(const uint4*)(bq);      b1 = *(const uint4*)(bq + 8);
                b2 = *(const uint4*)(bq + 16); b3 = *(const uint4*)(bq + 24);
            }
        }
        __syncthreads();

        short8 af = *(const short8*)&As[w * 16 + ll][q * 8];
#pragma unroll
        for (int c = 0; c < 12; c++) {
            short8 bf = *(const short8*)&Bs[c * 16 + ll][q * 8];
            acc[c] = __builtin_amdgcn_mfma_f32_16x16x32_bf16(af, bf, acc[c], 0, 0, 0);
        }
    }

    // ---- epilogue: el/er (full head dots) + hb store ----
    float al[12], ar[12];
#pragma unroll
    for (int c = 0; c < 12; c++) {
        al[c] = attn_l[c * 16 + ll];
        ar[c] = attn_r[c * 16 + ll];
    }
    float sl[3][4], sr_[3][4];
#pragma unroll
    for (int hd = 0; hd < 3; hd++)
#pragma unroll
        for (int i = 0; i < 4; i++) {
            float a = 0.f, b = 0.f;
#pragma unroll
            for (int f = 0; f < 4; f++) {
                a = fmaf(acc[hd * 4 + f][i], al[hd * 4 + f], a);
                b = fmaf(acc[hd * 4 + f][i], ar[hd * 4 + f], b);
            }
            sl[hd][i] = a; sr_[hd][i] = b;
        }
#pragma unroll
    for (int hd = 0; hd < 3; hd++)
#pragma unroll
        for (int i = 0; i < 4; i++)
#pragma unroll
            for (int off = 1; off < 16; off <<= 1) {
                sl[hd][i]  += __shfl_xor(sl[hd][i],  off, 64);
                sr_[hd][i] += __shfl_xor(sr_[hd][i], off, 64);
            }
#pragma unroll
    for (int c = 0; c < 12; c++)
#pragma unroll
        for (int i = 0; i < 4; i++) {
            int row = row0 + w * 16 + q * 4 + i;
            if (row < M)
                hb[(size_t)row * HD + c * 16 + ll] = __float2bfloat16(acc[c][i]);
        }
    if (ll == 0) {
#pragma unroll
        for (int i = 0; i < 4; i++) {
            int row = row0 + w * 16 + q * 4 + i;
            if (row < M) {
#pragma unroll
                for (int hd = 0; hd < 3; hd++) {
                    el[row * 4 + hd] = sl[hd][i];    // padded float4 stride
                    er[row * 4 + hd] = sr_[hd][i];
                }
            }
        }
    }
}

// ---------------------------------------------------------------------------
// K2: fused bucket kernel. Block = 16-node fine region, 1024 threads,
// 16 waves, ONE NODE PER WAVE (20000 waves offered -> 100% resident
// occupancy + backfill; round-4's 4-nodes-serial-per-wave gave only 5000
// waves / 25% occ). The block scans its 128-node COARSE bucket's dense
// pair run (coalesced; 8x re-read traded for balance+occupancy), filters
// its 16 nodes, ranks into a 6KB LDS ELL, then each wave runs softmax +
// aggregation + bias/relu + fc dot for its node.
// ---------------------------------------------------------------------------
__global__ __launch_bounds__(1024) void gat_bucket_kernel(
    const __hip_bfloat16* __restrict__ h, const float* __restrict__ el,
    const float* __restrict__ er, const int2* __restrict__ pairs,
    const int* __restrict__ gCur, const float* __restrict__ gbias,
    const float* __restrict__ fc_w, float* __restrict__ pA,
    float* __restrict__ pB, int N)
{
    __shared__ int cur[FNODES];
    __shared__ int lell[FNODES][LPAD];
    __shared__ float4 sE[16][64];   // per-wave edge slots: (s_bits, w0, w1, w2)

    const int bid = blockIdx.x;
    const int tid = threadIdx.x;
    const int lane = tid & 63, wslot = tid >> 6;
    const int cb = bid >> 3, sub = bid & 7;   // coarse bucket, 16-node slice

    if (tid < FNODES) cur[tid] = 0;
    __syncthreads();
    const int pcnt = min(gCur[cb], BCAP);
    const int2* pp = pairs + (size_t)cb * BCAP;
    for (int i = tid; i < pcnt; i += 1024) {
        int2 p = pp[i];
        int nl = p.x & 127;
        if ((nl >> 4) == sub) {
            int f = nl & 15;
            int r = atomicAdd(&cur[f], 1);
            if (r < ELLPAD) lell[f][r] = p.y;
        }
    }
    __syncthreads();

    const int v = bid * FNODES + wslot;   // wave wslot handles node v
    if (v >= N) return;

    const int cnt = min(cur[wslot], ELLPAD);
    const int* rowp = &lell[wslot][0];
    const float4 erv = ((const float4*)er)[v];
    const float er0 = erv.x, er1 = erv.y, er2 = erv.z;
    const __hip_bfloat16* hl = h + lane;

    float acc0 = 0.f, acc1 = 0.f, acc2 = 0.f;
    float d0 = 0.f, d1 = 0.f, d2 = 0.f;

    for (int chunk = 0; chunk < cnt; chunk += 64) {
        const int i = chunk + lane;
        float w0 = 0.f, w1 = 0.f, w2 = 0.f;
        int s = 0;
        if (i < cnt) {
            s = rowp[i];                         // LDS read
            const float4 le = ((const float4*)el)[s];
            float l0 = le.x + er0;
            float l1 = le.y + er1;
            float l2 = le.z + er2;
            l0 = l0 > 0.f ? l0 : NEG_SLOPE * l0;
            l1 = l1 > 0.f ? l1 : NEG_SLOPE * l1;
            l2 = l2 > 0.f ? l2 : NEG_SLOPE * l2;
            w0 = __expf(l0); w1 = __expf(l1); w2 = __expf(l2);
        }
        d0 += w0; d1 += w1; d2 += w2;
        sE[wslot][lane] = make_float4(__int_as_float(s), w0, w1, w2);
        // same-wave LDS write->read; drain DS queue before readback:
        __asm__ volatile("s_waitcnt lgkmcnt(0)" ::: "memory");

        const int rem = min(cnt - chunk, 64);
        const int nR = (rem + 7) & ~7;   // pad entries have w=0, s=0
        for (int j = 0; j < nR; j += 8) {
            float4 e[8];
#pragma unroll
            for (int u = 0; u < 8; u++) e[u] = sE[wslot][j + u];
            float x0[8], x1[8], x2[8];
#pragma unroll
            for (int u = 0; u < 8; u++) {
                const __hip_bfloat16* p = hl + (size_t)__float_as_int(e[u].x) * HD;
                x0[u] = __bfloat162float(p[0]);
                x1[u] = __bfloat162float(p[64]);
                x2[u] = __bfloat162float(p[128]);
            }
#pragma unroll
            for (int u = 0; u < 8; u++) {
                acc0 = fmaf(e[u].y, x0[u], acc0);
                acc1 = fmaf(e[u].z, x1[u], acc1);
                acc2 = fmaf(e[u].w, x2[u], acc2);
            }
        }
    }

    d0 = wave_sum(d0); d1 = wave_sum(d1); d2 = wave_sum(d2);

    float o0 = (d0 > 0.f) ? acc0 / d0 : 0.f;
    float o1 = (d1 > 0.f) ? acc1 / d1 : 0.f;
    float o2 = (d2 > 0.f) ? acc2 / d2 : 0.f;
    o0 = fmaxf(o0 + gbias[lane], 0.f);
    o1 = fmaxf(o1 + gbias[64 + lane], 0.f);
    o2 = fmaxf(o2 + gbias[128 + lane], 0.f);

    const size_t bidx = (size_t)v * HD;
    float2 w0v = ((const float2*)fc_w)[bidx + lane];
    float2 w1v = ((const float2*)fc_w)[bidx + 64 + lane];
    float2 w2v = ((const float2*)fc_w)[bidx + 128 + lane];
    float f0 = fmaf(o0, w0v.x, fmaf(o1, w1v.x, o2 * w2v.x));
    float f1 = fmaf(o0, w0v.y, fmaf(o1, w1v.y, o2 * w2v.y));

    f0 = wave_sum(f0); f1 = wave_sum(f1);
    if (lane == 0) { pA[v] = f0; pB[v] = f1; }
}

// ---------------------------------------------------------------------------
// K4: final reduction of per-node partials -> out (adds fc bias; no atomics)
// ---------------------------------------------------------------------------
__global__ __launch_bounds__(1024) void final_reduce(const float* __restrict__ pA,
                                                     const float* __restrict__ pB,
                                                     const float* __restrict__ fc_b,
                                                     float* __restrict__ out, int nb)
{
    int tid = threadIdx.x;
    float s0 = 0.f, s1 = 0.f;
    for (int i = tid; i < nb; i += 1024) { s0 += pA[i]; s1 += pB[i]; }
    s0 = wave_sum(s0); s1 = wave_sum(s1);
    __shared__ float sh[32];
    int lane = tid & 63, w = tid >> 6;
    if (lane == 0) { sh[w * 2] = s0; sh[w * 2 + 1] = s1; }
    __syncthreads();
    if (tid == 0) {
        float t0 = 0.f, t1 = 0.f;
#pragma unroll
        for (int i = 0; i < 16; i++) { t0 += sh[i * 2]; t1 += sh[i * 2 + 1]; }
        out[0] = t0 + fc_b[0];
        out[1] = t1 + fc_b[1];
    }
}

// ---------------------------------------------------------------------------
extern "C" void kernel_launch(void* const* d_in, const int* in_sizes, int n_in,
                              void* d_out, int out_size, void* d_ws, size_t ws_size,
                              hipStream_t stream)
{
    const float* feat   = (const float*)d_in[0];
    const float* W      = (const float*)d_in[1];
    const float* attn_l = (const float*)d_in[2];
    const float* attn_r = (const float*)d_in[3];
    const float* gbias  = (const float*)d_in[4];
    const float* fc_w   = (const float*)d_in[5];
    const float* fc_b   = (const float*)d_in[6];
    const int*   src    = (const int*)d_in[7];
    const int*   dst    = (const int*)d_in[8];

    const int N = in_sizes[0] / INDIM;   // 20000
    const int E = in_sizes[7];           // 640000
    const int nFine = (N + FNODES - 1) / FNODES;   // 1250

    // workspace layout (~15 MB, all sub-arrays 16B-aligned)
    __hip_bfloat16* Wt = (__hip_bfloat16*)d_ws;             // 192*256       (96 KB)
    __hip_bfloat16* hb = Wt + HD * INDIM;                   // N*192         (7.68 MB)
    float* el = (float*)(hb + (size_t)N * HD);              // N*4 (padded)
    float* er = el + (size_t)N * 4;                         // N*4 (padded)
    int* gCur = (int*)(er + (size_t)N * 4);                 // NBUCK (160)
    int2* pairs = (int2*)(gCur + NBUCK);                    // NBUCK*BCAP    (5.9 MB)
    float* pA = (float*)(pairs + (size_t)NBUCK * BCAP);     // N
    float* pB = pA + N;                                     // N

    prep_kernel<<<1 + HD, 256, 0, stream>>>(W, Wt, gCur);

    const int gemmBlocks = (N + 63) / 64;
    const int p1Blocks = (E + P1CHUNK - 1) / P1CHUNK;
    gemm_bucket_kernel<<<gemmBlocks + p1Blocks, 256, 0, stream>>>(
        feat, Wt, attn_l, attn_r, hb, el, er, N,
        src, dst, gCur, pairs, E, gemmBlocks);

    gat_bucket_kernel<<<nFine, 1024, 0, stream>>>(hb, el, er, pairs, gCur,
                                                  gbias, fc_w, pA, pB, N);
    final_reduce<<<1, 1024, 0, stream>>>(pA, pB, fc_b, (float*)d_out, N);
}